// Round 1
// baseline (4946.450 us; speedup 1.0000x reference)
//
#include <hip/hip_runtime.h>
#include <math.h>

// Per-sample fully-fused iterated CNN. Persistent blocks (3/CU), 256 threads,
// atomic work-stealing over samples so the 1024-sample pool stays balanced at
// 3 resident blocks/CU (1024 blocks at 3/CU would leave a 256-block tail).
// LDS strides padded for bank-conflict avoidance / float4 alignment:
#define RP32S 36   // zero-padded 32x36 state for conv1 (16B-aligned rows)
#define RP40S 44   // (-1)-padded 40x44 state for depthwise (16B-aligned rows)
#define H1S   31   // h1 planes 31x31 zero-padded (stride 31 ~= -1 mod 32: conflict-free)

struct SharedBufs {
    float rp32[32*RP32S];   //  4608 B
    float rp40[40*RP40S];   //  7040 B
    float h1p[8*H1S*H1S];   // 30752 B
    float pbuf[1296];       //  5184 B  (pooled feats; reused as new-r tmp[784])
    float wker[169];        //   676 B
    float w1s[200];         //   800 B
    float b1s[8];
    float b2s[16];
    float num_s[10];
    int   next;             // work-stealing broadcast slot
};                          // ~49.2 KB -> 3 blocks/CU (w2 now read from L1/L2)

template<int OUT>
__device__ __forceinline__ void fc_tanh(const float* __restrict__ Wg,
                                        const float* __restrict__ bg,
                                        const float* __restrict__ p,
                                        float* __restrict__ dst, int tid)
{
    if (tid < OUT) {
        float a[8];
        #pragma unroll
        for (int u = 0; u < 8; ++u) a[u] = 0.f;
        #pragma unroll 2
        for (int i0 = 0; i0 < 1296; i0 += 8) {
            #pragma unroll
            for (int u = 0; u < 8; ++u)
                a[u] = fmaf(p[i0+u], Wg[(i0+u)*OUT + tid], a[u]);
        }
        float s = ((a[0]+a[1])+(a[2]+a[3])) + ((a[4]+a[5])+(a[6]+a[7])) + bg[tid];
        dst[tid] = tanhf(s);
    }
}

__device__ __forceinline__ void trunk_pass(SharedBufs& sb, int tid,
                                           const float* __restrict__ w2g)
{
    // ---- conv1 5x5 pad2 + relu -> h1p. thread = (y, c): c=tid&7 so a y-group
    // of 8 lanes broadcasts the same rp32 row (no bank conflicts).
    if (tid < 224) {
        const int c = tid & 7;
        const int y = tid >> 3;
        const float bias = sb.b1s[c];
        float acc[28];
        #pragma unroll
        for (int x = 0; x < 28; ++x) acc[x] = bias;
        const float* wb = &sb.w1s[c*25];
        #pragma unroll
        for (int ky = 0; ky < 5; ++ky) {
            const float4* rr = (const float4*)&sb.rp32[(y+ky)*RP32S];
            float rv[32];
            #pragma unroll
            for (int q = 0; q < 8; ++q) {
                float4 t = rr[q];
                rv[q*4+0]=t.x; rv[q*4+1]=t.y; rv[q*4+2]=t.z; rv[q*4+3]=t.w;
            }
            #pragma unroll
            for (int kx = 0; kx < 5; ++kx) {
                const float w = wb[ky*5+kx];
                #pragma unroll
                for (int x = 0; x < 28; ++x) acc[x] = fmaf(w, rv[x+kx], acc[x]);
            }
        }
        float* hp = &sb.h1p[(c*H1S + y + 2)*H1S + 2];
        #pragma unroll
        for (int x = 0; x < 28; ++x) hp[x] = fmaxf(acc[x], 0.f);
    }
    __syncthreads();

    // ---- conv2 5x5 pad2 + relu + maxpool3 -> pbuf[1296].
    // thread computes a 2(py) x 3(px) group of pooled outputs: 54 conv accs,
    // FMA:LDS ~ 8.7:1 via row-register reuse. 240 threads cover 16c x 5pyg x 3pxg.
    // w2 is read straight from global: 12.8 KB, shared by every block -> L1/L2
    // resident; 15 lanes share each c so reads coalesce/broadcast.
    if (tid < 240) {
        const int c    = tid / 15;
        const int rem  = tid % 15;
        const int pyg  = rem / 3;
        const int pxg  = rem % 3;
        const int row0 = pyg * 6;   // first padded h1 row needed
        const int col0 = pxg * 9;   // first padded h1 col needed
        const float bias = sb.b2s[c];
        float acc[54];              // acc[t*9+u]: conv rows t=0..5, cols u=0..8
        #pragma unroll
        for (int i = 0; i < 54; ++i) acc[i] = bias;
        for (int ic = 0; ic < 8; ++ic) {
            float wreg[25];
            const float* wsrc = &w2g[(c*8+ic)*25];
            #pragma unroll
            for (int t = 0; t < 25; ++t) wreg[t] = wsrc[t];
            #pragma unroll
            for (int yy = 0; yy < 10; ++yy) {
                int rr = row0 + yy; rr = rr > 30 ? 30 : rr;  // clamp for pyg==4 (h=1 outputs discarded)
                const float* hp = &sb.h1p[(ic*H1S + rr)*H1S + col0];
                float rowv[13];
                #pragma unroll
                for (int j = 0; j < 13; ++j) rowv[j] = hp[j];
                #pragma unroll
                for (int t = 0; t < 6; ++t) {
                    const int ky = yy - t;
                    if (ky < 0 || ky > 4) continue;  // static after unroll
                    #pragma unroll
                    for (int kx = 0; kx < 5; ++kx) {
                        const float w = wreg[ky*5+kx];
                        #pragma unroll
                        for (int u = 0; u < 9; ++u)
                            acc[t*9+u] = fmaf(w, rowv[u+kx], acc[t*9+u]);
                    }
                }
            }
        }
        #pragma unroll
        for (int h = 0; h < 2; ++h) {
            const int py = pyg*2 + h;
            if (py < 9) {
                #pragma unroll
                for (int pxi = 0; pxi < 3; ++pxi) {
                    float m = acc[(h*3)*9 + pxi*3];
                    #pragma unroll
                    for (int dy = 0; dy < 3; ++dy)
                        #pragma unroll
                        for (int dx = 0; dx < 3; ++dx)
                            m = fmaxf(m, acc[(h*3+dy)*9 + pxi*3 + dx]);
                    sb.pbuf[c*81 + py*9 + pxg*3 + pxi] = fmaxf(m, 0.f);
                }
            }
        }
    }
    __syncthreads();
}

__device__ __forceinline__ void depthwise13(SharedBufs& sb, int tid)
{
    // out(y,x) = sum_{ky,kx} wker[ky*13+kx] * rp40[y+ky][x+kx]; 4 outputs/thread.
    if (tid < 196) {
        const int y  = tid / 7;
        const int x0 = (tid % 7) * 4;
        float a0=0.f, a1=0.f, a2=0.f, a3=0.f;
        #pragma unroll 1
        for (int ky = 0; ky < 13; ++ky) {
            const float4* rr = (const float4*)&sb.rp40[(y+ky)*RP40S + x0];
            float rv[16];
            #pragma unroll
            for (int q = 0; q < 4; ++q) {
                float4 t = rr[q];
                rv[q*4+0]=t.x; rv[q*4+1]=t.y; rv[q*4+2]=t.z; rv[q*4+3]=t.w;
            }
            const float* wr = &sb.wker[ky*13];
            #pragma unroll
            for (int kx = 0; kx < 13; ++kx) {
                const float w = wr[kx];
                a0 = fmaf(w, rv[kx+0], a0);
                a1 = fmaf(w, rv[kx+1], a1);
                a2 = fmaf(w, rv[kx+2], a2);
                a3 = fmaf(w, rv[kx+3], a3);
            }
        }
        float* dp = &sb.pbuf[y*28 + x0];
        dp[0]=a0; dp[1]=a1; dp[2]=a2; dp[3]=a3;
    }
}

__global__ __launch_bounds__(256, 3)
void modeld_fused(const float* __restrict__ x,
                  const float* __restrict__ n_w1, const float* __restrict__ n_b1,
                  const float* __restrict__ n_w2, const float* __restrict__ n_b2,
                  const float* __restrict__ n_wl, const float* __restrict__ n_bl,
                  const float* __restrict__ c_w1, const float* __restrict__ c_b1,
                  const float* __restrict__ c_w2, const float* __restrict__ c_b2,
                  const float* __restrict__ c_wl, const float* __restrict__ c_bl,
                  float* __restrict__ out,
                  int* __restrict__ counter, int B)
{
    __shared__ SharedBufs sb;
    const int tid = threadIdx.x;

    // one-time pad init: pads persist across samples (only interiors rewritten)
    for (int i = tid; i < 32*RP32S;  i += 256) sb.rp32[i] = 0.f;
    for (int i = tid; i < 40*RP40S;  i += 256) sb.rp40[i] = -1.f;
    for (int i = tid; i < 8*H1S*H1S; i += 256) sb.h1p[i]  = 0.f;

    while (true) {
        if (tid == 0) sb.next = atomicAdd(counter, 1);
        __syncthreads();                       // also orders pad init / prev sample
        const int b = sb.next;
        if (b >= B) break;                     // uniform exit

        // load x into both padded state buffers; keep own values in regs
        float cur[4] = {0.f, 0.f, 0.f, 0.f};
        #pragma unroll
        for (int q = 0; q < 4; ++q) {
            int i = tid + q*256;
            if (i < 784) {
                float v = x[b*784 + i];
                cur[q] = v;
                int yy = i / 28, xx = i % 28;
                sb.rp32[(yy+2)*RP32S + xx + 2] = v;
                sb.rp40[(yy+6)*RP40S + xx + 6] = v;
            }
        }
        // stage n-weights (w2 stays in global)
        for (int i = tid; i < 200; i += 256) sb.w1s[i] = n_w1[i];
        if (tid < 8)  sb.b1s[tid] = n_b1[tid];
        if (tid < 16) sb.b2s[tid] = n_b2[tid];
        __syncthreads();

        // ---- n-trunk -> num[0..9]
        trunk_pass(sb, tid, n_w2);
        fc_tanh<10>(n_wl, n_bl, sb.pbuf, sb.num_s, tid);
        __syncthreads();

        float o[4];
        {
            const float n0 = sb.num_s[0];
            #pragma unroll
            for (int q = 0; q < 4; ++q) o[q] = n0 * cur[q];
        }
        // stage c-weights (trunk + FC done; safe to overwrite)
        for (int i = tid; i < 200; i += 256) sb.w1s[i] = c_w1[i];
        if (tid < 8)  sb.b1s[tid] = c_b1[tid];
        if (tid < 16) sb.b2s[tid] = c_b2[tid];
        __syncthreads();

        // ---- 9 iterations
        for (int k = 1; k <= 9; ++k) {
            trunk_pass(sb, tid, c_w2);                         // rp32 -> pbuf[1296]
            fc_tanh<169>(c_wl, c_bl, sb.pbuf, sb.wker, tid);   // pbuf -> wker
            __syncthreads();
            depthwise13(sb, tid);                              // rp40,wker -> pbuf[0..783]
            __syncthreads();
            const float nk = sb.num_s[k];
            #pragma unroll
            for (int q = 0; q < 4; ++q) {
                int i = tid + q*256;
                if (i < 784) {
                    float v = sb.pbuf[i];
                    o[q] = fmaf(nk, v, o[q]);
                    int yy = i / 28, xx = i % 28;
                    sb.rp32[(yy+2)*RP32S + xx + 2] = v;
                    sb.rp40[(yy+6)*RP40S + xx + 6] = v;
                }
            }
            __syncthreads();
        }

        #pragma unroll
        for (int q = 0; q < 4; ++q) {
            int i = tid + q*256;
            if (i < 784) out[b*784 + i] = o[q];
        }
        // no barrier needed here: next iteration's grab+sync orders sb.next,
        // and all LDS writes for the next sample happen after that sync.
    }
}

extern "C" void kernel_launch(void* const* d_in, const int* in_sizes, int n_in,
                              void* d_out, int out_size, void* d_ws, size_t ws_size,
                              hipStream_t stream)
{
    const float* x    = (const float*)d_in[0];
    const float* n_w1 = (const float*)d_in[1];
    const float* n_b1 = (const float*)d_in[2];
    const float* n_w2 = (const float*)d_in[3];
    const float* n_b2 = (const float*)d_in[4];
    const float* n_wl = (const float*)d_in[5];
    const float* n_bl = (const float*)d_in[6];
    const float* c_w1 = (const float*)d_in[7];
    const float* c_b1 = (const float*)d_in[8];
    const float* c_w2 = (const float*)d_in[9];
    const float* c_b2 = (const float*)d_in[10];
    const float* c_wl = (const float*)d_in[11];
    const float* c_bl = (const float*)d_in[12];
    float* out = (float*)d_out;

    const int B = in_sizes[0] / 784;
    hipMemsetAsync(d_ws, 0, sizeof(int), stream);   // work-stealing counter reset
    const int grid = B < 768 ? B : 768;             // 3 blocks/CU x 256 CUs
    hipLaunchKernelGGL(modeld_fused, dim3(grid), dim3(256), 0, stream,
                       x, n_w1, n_b1, n_w2, n_b2, n_wl, n_bl,
                       c_w1, c_b1, c_w2, c_b2, c_wl, c_bl, out,
                       (int*)d_ws, B);
}

// Round 2
// 1643.641 us; speedup vs baseline: 3.0094x; 3.0094x over previous
//
#include <hip/hip_runtime.h>
#include <math.h>

// Per-sample fully-fused iterated CNN. Persistent blocks (3/CU via LDS+VGPR
// natural limits -- NO register-capping launch_bounds: (256,3) forced VGPR=84
// and spilled ~18 GB/dispatch to scratch in round 1), 256 threads, atomic
// work-stealing over samples so the pool stays balanced at 3 resident
// blocks/CU with no tail-drain.
// LDS strides padded for bank-conflict avoidance / float4 alignment:
#define RP32S 36   // zero-padded 32x36 state for conv1 (16B-aligned rows)
#define RP40S 44   // (-1)-padded 40x44 state for depthwise (16B-aligned rows)
#define H1S   31   // h1 planes 31x31 zero-padded (stride 31 ~= -1 mod 32: conflict-free)

struct SharedBufs {
    float rp32[32*RP32S];   //  4608 B
    float rp40[40*RP40S];   //  7040 B
    float h1p[8*H1S*H1S];   // 30752 B
    float pbuf[1296];       //  5184 B  (pooled feats; reused as new-r tmp[784])
    float wker[169];        //   676 B
    float w1s[200];         //   800 B
    float b1s[8];
    float b2s[16];
    float num_s[10];
    int   next;             // work-stealing broadcast slot
};                          // ~49.2 KB -> 3 blocks/CU (w2 read from L1/L2)

template<int OUT>
__device__ __forceinline__ void fc_tanh(const float* __restrict__ Wg,
                                        const float* __restrict__ bg,
                                        const float* __restrict__ p,
                                        float* __restrict__ dst, int tid)
{
    if (tid < OUT) {
        float a[8];
        #pragma unroll
        for (int u = 0; u < 8; ++u) a[u] = 0.f;
        #pragma unroll 2
        for (int i0 = 0; i0 < 1296; i0 += 8) {
            #pragma unroll
            for (int u = 0; u < 8; ++u)
                a[u] = fmaf(p[i0+u], Wg[(i0+u)*OUT + tid], a[u]);
        }
        float s = ((a[0]+a[1])+(a[2]+a[3])) + ((a[4]+a[5])+(a[6]+a[7])) + bg[tid];
        dst[tid] = tanhf(s);
    }
}

__device__ __forceinline__ void trunk_pass(SharedBufs& sb, int tid,
                                           const float* __restrict__ w2g)
{
    // ---- conv1 5x5 pad2 + relu -> h1p. thread = (y, c): c=tid&7 so a y-group
    // of 8 lanes broadcasts the same rp32 row (no bank conflicts).
    if (tid < 224) {
        const int c = tid & 7;
        const int y = tid >> 3;
        const float bias = sb.b1s[c];
        float acc[28];
        #pragma unroll
        for (int x = 0; x < 28; ++x) acc[x] = bias;
        const float* wb = &sb.w1s[c*25];
        #pragma unroll
        for (int ky = 0; ky < 5; ++ky) {
            const float4* rr = (const float4*)&sb.rp32[(y+ky)*RP32S];
            float rv[32];
            #pragma unroll
            for (int q = 0; q < 8; ++q) {
                float4 t = rr[q];
                rv[q*4+0]=t.x; rv[q*4+1]=t.y; rv[q*4+2]=t.z; rv[q*4+3]=t.w;
            }
            #pragma unroll
            for (int kx = 0; kx < 5; ++kx) {
                const float w = wb[ky*5+kx];
                #pragma unroll
                for (int x = 0; x < 28; ++x) acc[x] = fmaf(w, rv[x+kx], acc[x]);
            }
        }
        float* hp = &sb.h1p[(c*H1S + y + 2)*H1S + 2];
        #pragma unroll
        for (int x = 0; x < 28; ++x) hp[x] = fmaxf(acc[x], 0.f);
    }
    __syncthreads();

    // ---- conv2 5x5 pad2 + relu + maxpool3 -> pbuf[1296].
    // thread computes a 2(py) x 3(px) group of pooled outputs: 54 conv accs,
    // FMA:LDS ~ 8.7:1 via row-register reuse. 240 threads cover 16c x 5pyg x 3pxg.
    // w2 is read straight from global: 12.8 KB, shared by every block -> L1/L2
    // resident; 15 lanes share each c so reads coalesce/broadcast.
    if (tid < 240) {
        const int c    = tid / 15;
        const int rem  = tid % 15;
        const int pyg  = rem / 3;
        const int pxg  = rem % 3;
        const int row0 = pyg * 6;   // first padded h1 row needed
        const int col0 = pxg * 9;   // first padded h1 col needed
        const float bias = sb.b2s[c];
        float acc[54];              // acc[t*9+u]: conv rows t=0..5, cols u=0..8
        #pragma unroll
        for (int i = 0; i < 54; ++i) acc[i] = bias;
        for (int ic = 0; ic < 8; ++ic) {
            float wreg[25];
            const float* wsrc = &w2g[(c*8+ic)*25];
            #pragma unroll
            for (int t = 0; t < 25; ++t) wreg[t] = wsrc[t];
            #pragma unroll
            for (int yy = 0; yy < 10; ++yy) {
                int rr = row0 + yy; rr = rr > 30 ? 30 : rr;  // clamp for pyg==4 (h=1 outputs discarded)
                const float* hp = &sb.h1p[(ic*H1S + rr)*H1S + col0];
                float rowv[13];
                #pragma unroll
                for (int j = 0; j < 13; ++j) rowv[j] = hp[j];
                #pragma unroll
                for (int t = 0; t < 6; ++t) {
                    const int ky = yy - t;
                    if (ky < 0 || ky > 4) continue;  // static after unroll
                    #pragma unroll
                    for (int kx = 0; kx < 5; ++kx) {
                        const float w = wreg[ky*5+kx];
                        #pragma unroll
                        for (int u = 0; u < 9; ++u)
                            acc[t*9+u] = fmaf(w, rowv[u+kx], acc[t*9+u]);
                    }
                }
            }
        }
        #pragma unroll
        for (int h = 0; h < 2; ++h) {
            const int py = pyg*2 + h;
            if (py < 9) {
                #pragma unroll
                for (int pxi = 0; pxi < 3; ++pxi) {
                    float m = acc[(h*3)*9 + pxi*3];
                    #pragma unroll
                    for (int dy = 0; dy < 3; ++dy)
                        #pragma unroll
                        for (int dx = 0; dx < 3; ++dx)
                            m = fmaxf(m, acc[(h*3+dy)*9 + pxi*3 + dx]);
                    sb.pbuf[c*81 + py*9 + pxg*3 + pxi] = fmaxf(m, 0.f);
                }
            }
        }
    }
    __syncthreads();
}

__device__ __forceinline__ void depthwise13(SharedBufs& sb, int tid)
{
    // out(y,x) = sum_{ky,kx} wker[ky*13+kx] * rp40[y+ky][x+kx]; 4 outputs/thread.
    if (tid < 196) {
        const int y  = tid / 7;
        const int x0 = (tid % 7) * 4;
        float a0=0.f, a1=0.f, a2=0.f, a3=0.f;
        #pragma unroll 1
        for (int ky = 0; ky < 13; ++ky) {
            const float4* rr = (const float4*)&sb.rp40[(y+ky)*RP40S + x0];
            float rv[16];
            #pragma unroll
            for (int q = 0; q < 4; ++q) {
                float4 t = rr[q];
                rv[q*4+0]=t.x; rv[q*4+1]=t.y; rv[q*4+2]=t.z; rv[q*4+3]=t.w;
            }
            const float* wr = &sb.wker[ky*13];
            #pragma unroll
            for (int kx = 0; kx < 13; ++kx) {
                const float w = wr[kx];
                a0 = fmaf(w, rv[kx+0], a0);
                a1 = fmaf(w, rv[kx+1], a1);
                a2 = fmaf(w, rv[kx+2], a2);
                a3 = fmaf(w, rv[kx+3], a3);
            }
        }
        float* dp = &sb.pbuf[y*28 + x0];
        dp[0]=a0; dp[1]=a1; dp[2]=a2; dp[3]=a3;
    }
}

__global__ __launch_bounds__(256)
void modeld_fused(const float* __restrict__ x,
                  const float* __restrict__ n_w1, const float* __restrict__ n_b1,
                  const float* __restrict__ n_w2, const float* __restrict__ n_b2,
                  const float* __restrict__ n_wl, const float* __restrict__ n_bl,
                  const float* __restrict__ c_w1, const float* __restrict__ c_b1,
                  const float* __restrict__ c_w2, const float* __restrict__ c_b2,
                  const float* __restrict__ c_wl, const float* __restrict__ c_bl,
                  float* __restrict__ out,
                  int* __restrict__ counter, int B)
{
    __shared__ SharedBufs sb;
    const int tid = threadIdx.x;

    // one-time pad init: pads persist across samples (only interiors rewritten)
    for (int i = tid; i < 32*RP32S;  i += 256) sb.rp32[i] = 0.f;
    for (int i = tid; i < 40*RP40S;  i += 256) sb.rp40[i] = -1.f;
    for (int i = tid; i < 8*H1S*H1S; i += 256) sb.h1p[i]  = 0.f;

    while (true) {
        if (tid == 0) sb.next = atomicAdd(counter, 1);
        __syncthreads();                       // also orders pad init / prev sample
        const int b = sb.next;
        if (b >= B) break;                     // uniform exit

        // load x into both padded state buffers; keep own values in regs
        float cur[4] = {0.f, 0.f, 0.f, 0.f};
        #pragma unroll
        for (int q = 0; q < 4; ++q) {
            int i = tid + q*256;
            if (i < 784) {
                float v = x[b*784 + i];
                cur[q] = v;
                int yy = i / 28, xx = i % 28;
                sb.rp32[(yy+2)*RP32S + xx + 2] = v;
                sb.rp40[(yy+6)*RP40S + xx + 6] = v;
            }
        }
        // stage n-weights (w2 stays in global)
        for (int i = tid; i < 200; i += 256) sb.w1s[i] = n_w1[i];
        if (tid < 8)  sb.b1s[tid] = n_b1[tid];
        if (tid < 16) sb.b2s[tid] = n_b2[tid];
        __syncthreads();

        // ---- n-trunk -> num[0..9]
        trunk_pass(sb, tid, n_w2);
        fc_tanh<10>(n_wl, n_bl, sb.pbuf, sb.num_s, tid);
        __syncthreads();

        float o[4];
        {
            const float n0 = sb.num_s[0];
            #pragma unroll
            for (int q = 0; q < 4; ++q) o[q] = n0 * cur[q];
        }
        // stage c-weights (trunk + FC done; safe to overwrite)
        for (int i = tid; i < 200; i += 256) sb.w1s[i] = c_w1[i];
        if (tid < 8)  sb.b1s[tid] = c_b1[tid];
        if (tid < 16) sb.b2s[tid] = c_b2[tid];
        __syncthreads();

        // ---- 9 iterations
        for (int k = 1; k <= 9; ++k) {
            trunk_pass(sb, tid, c_w2);                         // rp32 -> pbuf[1296]
            fc_tanh<169>(c_wl, c_bl, sb.pbuf, sb.wker, tid);   // pbuf -> wker
            __syncthreads();
            depthwise13(sb, tid);                              // rp40,wker -> pbuf[0..783]
            __syncthreads();
            const float nk = sb.num_s[k];
            #pragma unroll
            for (int q = 0; q < 4; ++q) {
                int i = tid + q*256;
                if (i < 784) {
                    float v = sb.pbuf[i];
                    o[q] = fmaf(nk, v, o[q]);
                    int yy = i / 28, xx = i % 28;
                    sb.rp32[(yy+2)*RP32S + xx + 2] = v;
                    sb.rp40[(yy+6)*RP40S + xx + 6] = v;
                }
            }
            __syncthreads();
        }

        #pragma unroll
        for (int q = 0; q < 4; ++q) {
            int i = tid + q*256;
            if (i < 784) out[b*784 + i] = o[q];
        }
        // no barrier needed here: next iteration's grab+sync orders sb.next,
        // and all LDS writes for the next sample happen after that sync.
    }
}

extern "C" void kernel_launch(void* const* d_in, const int* in_sizes, int n_in,
                              void* d_out, int out_size, void* d_ws, size_t ws_size,
                              hipStream_t stream)
{
    const float* x    = (const float*)d_in[0];
    const float* n_w1 = (const float*)d_in[1];
    const float* n_b1 = (const float*)d_in[2];
    const float* n_w2 = (const float*)d_in[3];
    const float* n_b2 = (const float*)d_in[4];
    const float* n_wl = (const float*)d_in[5];
    const float* n_bl = (const float*)d_in[6];
    const float* c_w1 = (const float*)d_in[7];
    const float* c_b1 = (const float*)d_in[8];
    const float* c_w2 = (const float*)d_in[9];
    const float* c_b2 = (const float*)d_in[10];
    const float* c_wl = (const float*)d_in[11];
    const float* c_bl = (const float*)d_in[12];
    float* out = (float*)d_out;

    const int B = in_sizes[0] / 784;
    hipMemsetAsync(d_ws, 0, sizeof(int), stream);   // work-stealing counter reset
    const int grid = B < 768 ? B : 768;             // 3 blocks/CU x 256 CUs
    hipLaunchKernelGGL(modeld_fused, dim3(grid), dim3(256), 0, stream,
                       x, n_w1, n_b1, n_w2, n_b2, n_wl, n_bl,
                       c_w1, c_b1, c_w2, c_b2, c_wl, c_bl, out,
                       (int*)d_ws, B);
}